// Round 1
// baseline (296.836 us; speedup 1.0000x reference)
//
#include <hip/hip_runtime.h>
#include <math.h>

// ---------------------------------------------------------------------------
// AttentionBlock: GN(4,256) -> QKV 1x1 conv -> 2-head attn (N=1024, hd=128)
// -> proj -> +residual.  B=16, C=256, H=W=32 (N=1024), fp32 in/out.
// Strategy: bf16 MFMA (16x16x32) for all GEMM-shaped work; fp32 GN stats,
// fp32 softmax state, fp32 residual add.
// ---------------------------------------------------------------------------

typedef __attribute__((ext_vector_type(8))) short bf16x8;   // 8 bf16 = 4 VGPRs
typedef __attribute__((ext_vector_type(4))) float f32x4;

#define L2E 1.44269504088896340736f

__device__ __forceinline__ unsigned short f2bf(float f) {
    union { float f; unsigned u; } v; v.f = f;
    unsigned r = (v.u + 0x7FFFu + ((v.u >> 16) & 1u)) >> 16;
    return (unsigned short)r;
}

// ---------------------------------------------------------------- GN stats
__global__ __launch_bounds__(256) void gn_stats(const float* __restrict__ x,
                                                float* __restrict__ stats) {
    int bg = blockIdx.x;                       // b*4+g, 64 blocks
    const float* xp = x + (size_t)bg * 65536;  // 64 ch * 1024 spatial contiguous
    float s = 0.f, s2 = 0.f;
    for (int i = threadIdx.x; i < 65536; i += 256) {
        float v = xp[i]; s += v; s2 += v * v;
    }
    for (int m = 1; m < 64; m <<= 1) { s += __shfl_xor(s, m); s2 += __shfl_xor(s2, m); }
    __shared__ float ls[8];
    int w = threadIdx.x >> 6, lane = threadIdx.x & 63;
    if (lane == 0) { ls[w] = s; ls[4 + w] = s2; }
    __syncthreads();
    if (threadIdx.x == 0) {
        float S = ls[0] + ls[1] + ls[2] + ls[3];
        float S2 = ls[4] + ls[5] + ls[6] + ls[7];
        float mean = S * (1.f / 65536.f);
        float var = S2 * (1.f / 65536.f) - mean * mean;
        stats[bg * 2] = mean;
        stats[bg * 2 + 1] = rsqrtf(var + 1e-5f);
    }
}

// --------------------------------------------- normalize + transpose -> bf16
// out Xnt layout: (b, n, c) with c contiguous  (B-operand wants K-contig rows)
__global__ __launch_bounds__(256) void gn_norm(const float* __restrict__ x,
                                               const float* __restrict__ stats,
                                               const float* __restrict__ gnw,
                                               const float* __restrict__ gnb,
                                               unsigned short* __restrict__ xnt) {
    int b = blockIdx.z, ct = blockIdx.y, nt = blockIdx.x;  // (16,4,16)
    float mean = stats[(b * 4 + ct) * 2];
    float rstd = stats[(b * 4 + ct) * 2 + 1];
    __shared__ unsigned short tile[64][66];   // [c_local][n_local], pad->66
    int tid = threadIdx.x;
    int nloc = tid & 63, c0 = tid >> 6;
    for (int i = 0; i < 16; i++) {
        int cl = c0 + i * 4;
        int c = ct * 64 + cl;
        float v = x[((size_t)b * 256 + c) * 1024 + nt * 64 + nloc];
        tile[cl][nloc] = f2bf((v - mean) * rstd * gnw[c] + gnb[c]);
    }
    __syncthreads();
    int cloc = tid & 63, n0 = tid >> 6;
    for (int i = 0; i < 16; i++) {
        int nl = n0 + i * 4;
        int n = nt * 64 + nl;
        xnt[((size_t)b * 1024 + n) * 256 + ct * 64 + cloc] = tile[cloc][nl];
    }
}

// ------------------------------------------------------- weights fp32->bf16
__global__ __launch_bounds__(256) void wconv(const float* __restrict__ wq,
                                             const float* __restrict__ wk,
                                             const float* __restrict__ wv,
                                             const float* __restrict__ wp,
                                             unsigned short* __restrict__ oq,
                                             unsigned short* __restrict__ ok,
                                             unsigned short* __restrict__ ov,
                                             unsigned short* __restrict__ op) {
    int idx = blockIdx.x * 256 + threadIdx.x;  // 1024 blocks -> 262144 threads
    int which = idx >> 16, i = idx & 65535;
    const float* src = (which == 0) ? wq : (which == 1) ? wk : (which == 2) ? wv : wp;
    unsigned short* dst = (which == 0) ? oq : (which == 1) ? ok : (which == 2) ? ov : op;
    // fold softmax scale (c*NH)^-0.5 = 512^-0.5 into wq
    float scl = (which == 0) ? 0.044194173824159216f : 1.0f;
    dst[i] = f2bf(src[i] * scl);
}

// --------------------------------------------------------------- QKV GEMM
// Y(768x1024) = [Wq;Wk;Wv](768x256) x Xn(256x1024) per batch.
// A-frag: W row-major (o,c). B-frag: Xnt (i,c). D: col=i(lane&15), row=quad*4+r.
// Epilogue: Q,K -> (bh, i, ch) hd-contig ; V -> (bh, ch, i) n-contig.
__global__ __launch_bounds__(256) void qkv_gemm(const unsigned short* __restrict__ wqb,
                                                const unsigned short* __restrict__ wkb,
                                                const unsigned short* __restrict__ wvb,
                                                const unsigned short* __restrict__ xnt,
                                                unsigned short* __restrict__ qt,
                                                unsigned short* __restrict__ kt,
                                                unsigned short* __restrict__ vv) {
    int b = blockIdx.z;
    int my = blockIdx.y;          // 0..5 : {q,q,k,k,v,v} x 128 rows
    int nx = blockIdx.x;          // 0..7
    int tid = threadIdx.x;
    int w = tid >> 6, lane = tid & 63, quad = lane >> 4, c4 = lane & 15;
    int wm = (w >> 1) * 64, wn = (w & 1) * 64;
    const unsigned short* wptr = (my < 2) ? wqb : (my < 4) ? wkb : wvb;
    int mbase = (my & 1) * 128 + wm;     // row within this weight's 256
    int nbase = nx * 128 + wn;           // spatial col base
    const unsigned short* xb = xnt + (size_t)b * 1024 * 256;

    f32x4 acc[4][4] = {};
    for (int k = 0; k < 256; k += 32) {
        bf16x8 af[4], bfr[4];
        for (int i = 0; i < 4; i++) {
            af[i] = *(const bf16x8*)(wptr + (mbase + i * 16 + c4) * 256 + k + quad * 8);
            bfr[i] = *(const bf16x8*)(xb + (size_t)(nbase + i * 16 + c4) * 256 + k + quad * 8);
        }
        for (int mi = 0; mi < 4; mi++)
            for (int ni = 0; ni < 4; ni++)
                acc[mi][ni] = __builtin_amdgcn_mfma_f32_16x16x32_bf16(
                    af[mi], bfr[ni], acc[mi][ni], 0, 0, 0);
    }

    int sel = my >> 1;  // 0=q 1=k 2=v
    for (int mi = 0; mi < 4; mi++)
        for (int ni = 0; ni < 4; ni++) {
            int o = mbase + mi * 16 + quad * 4;     // + r
            int i = nbase + ni * 16 + c4;
            int h = o >> 7, ch = o & 127;
            if (sel < 2) {
                ushort4 pk;
                pk.x = f2bf(acc[mi][ni][0]);
                pk.y = f2bf(acc[mi][ni][1]);
                pk.z = f2bf(acc[mi][ni][2]);
                pk.w = f2bf(acc[mi][ni][3]);
                unsigned short* dst = (sel == 0 ? qt : kt) +
                    (((size_t)(b * 2 + h) * 1024 + i) * 128 + ch);
                *(ushort4*)dst = pk;
            } else {
                for (int r = 0; r < 4; r++)
                    vv[((size_t)(b * 2 + h) * 128 + ch + r) * 1024 + i] =
                        f2bf(acc[mi][ni][r]);
            }
        }
}

// ------------------------------------------------------- flash attention
// block = (qtile, h, b). 4 waves, each owns 32 q-rows. hd=128, N=1024.
__global__ __launch_bounds__(256) void attn_kernel(const unsigned short* __restrict__ qt,
                                                   const unsigned short* __restrict__ kt,
                                                   const unsigned short* __restrict__ vv,
                                                   unsigned short* __restrict__ ot) {
    int b = blockIdx.z, h = blockIdx.y, qti = blockIdx.x;
    int bh = b * 2 + h;
    int tid = threadIdx.x, w = tid >> 6, lane = tid & 63, quad = lane >> 4, c4 = lane & 15;
    __shared__ __align__(16) unsigned short plds[4][32][136];  // per-wave P, pad 8

    const unsigned short* qb = qt + (size_t)bh * 1024 * 128;
    const unsigned short* kb = kt + (size_t)bh * 1024 * 128;
    const unsigned short* vb = vv + (size_t)bh * 128 * 1024;
    int qr0 = qti * 128 + w * 32;

    // Q fragments: rows qr0 + m*16 + c4, k = kk*32 + quad*8 (reused 8x)
    bf16x8 aq[2][4];
    for (int m = 0; m < 2; m++)
        for (int kk = 0; kk < 4; kk++)
            aq[m][kk] = *(const bf16x8*)(qb + (size_t)(qr0 + m * 16 + c4) * 128 + kk * 32 + quad * 8);

    float ms[2][4], lsum[2][4];
    for (int m = 0; m < 2; m++)
        for (int r = 0; r < 4; r++) { ms[m][r] = -INFINITY; lsum[m][r] = 0.f; }
    f32x4 oacc[2][8] = {};

    for (int jt = 0; jt < 8; jt++) {
        // ---- S = Q K^T (scale already folded into Q)
        f32x4 s[2][8] = {};
        for (int kk = 0; kk < 4; kk++)
            for (int n = 0; n < 8; n++) {
                bf16x8 bk = *(const bf16x8*)(kb + (size_t)(jt * 128 + n * 16 + c4) * 128 + kk * 32 + quad * 8);
                s[0][n] = __builtin_amdgcn_mfma_f32_16x16x32_bf16(aq[0][kk], bk, s[0][n], 0, 0, 0);
                s[1][n] = __builtin_amdgcn_mfma_f32_16x16x32_bf16(aq[1][kk], bk, s[1][n], 0, 0, 0);
            }
        // ---- online softmax (rows: m*16+quad*4+r ; cols: n*16+c4)
        for (int m = 0; m < 2; m++)
            for (int r = 0; r < 4; r++) {
                float mx = s[m][0][r];
                for (int n = 1; n < 8; n++) mx = fmaxf(mx, s[m][n][r]);
                mx = fmaxf(mx, __shfl_xor(mx, 1));
                mx = fmaxf(mx, __shfl_xor(mx, 2));
                mx = fmaxf(mx, __shfl_xor(mx, 4));
                mx = fmaxf(mx, __shfl_xor(mx, 8));
                float mold = ms[m][r];
                float mnew = fmaxf(mold, mx);
                float alpha = exp2f((mold - mnew) * L2E);
                float rs = 0.f;
                for (int n = 0; n < 8; n++) {
                    float p = exp2f((s[m][n][r] - mnew) * L2E);
                    s[m][n][r] = p;
                    rs += p;
                }
                rs += __shfl_xor(rs, 1);
                rs += __shfl_xor(rs, 2);
                rs += __shfl_xor(rs, 4);
                rs += __shfl_xor(rs, 8);
                lsum[m][r] = lsum[m][r] * alpha + rs;
                ms[m][r] = mnew;
                for (int n = 0; n < 8; n++) oacc[m][n][r] *= alpha;
            }
        // ---- P -> LDS (bf16), then A-frags for PV
        for (int m = 0; m < 2; m++)
            for (int n = 0; n < 8; n++)
                for (int r = 0; r < 4; r++)
                    plds[w][m * 16 + quad * 4 + r][n * 16 + c4] = f2bf(s[m][n][r]);
        __syncthreads();
        for (int kk = 0; kk < 4; kk++) {
            bf16x8 ap0 = *(const bf16x8*)&plds[w][c4][kk * 32 + quad * 8];
            bf16x8 ap1 = *(const bf16x8*)&plds[w][16 + c4][kk * 32 + quad * 8];
            for (int n = 0; n < 8; n++) {
                bf16x8 bv = *(const bf16x8*)(vb + (size_t)(n * 16 + c4) * 1024 + jt * 128 + kk * 32 + quad * 8);
                oacc[0][n] = __builtin_amdgcn_mfma_f32_16x16x32_bf16(ap0, bv, oacc[0][n], 0, 0, 0);
                oacc[1][n] = __builtin_amdgcn_mfma_f32_16x16x32_bf16(ap1, bv, oacc[1][n], 0, 0, 0);
            }
        }
        __syncthreads();
    }
    // ---- epilogue: Ot (b, i, c) bf16, c = h*128 + n*16 + c4
    for (int m = 0; m < 2; m++)
        for (int n = 0; n < 8; n++)
            for (int r = 0; r < 4; r++) {
                int i = qr0 + m * 16 + quad * 4 + r;
                int c = h * 128 + n * 16 + c4;
                float val = oacc[m][n][r] / lsum[m][r];
                ot[((size_t)b * 1024 + i) * 256 + c] = f2bf(val);
            }
}

// ------------------------------------------------------ proj + residual
__global__ __launch_bounds__(256) void proj_gemm(const unsigned short* __restrict__ wpb,
                                                 const unsigned short* __restrict__ ot,
                                                 const float* __restrict__ x,
                                                 float* __restrict__ out) {
    int b = blockIdx.z;
    int my = blockIdx.y;   // 0..1
    int nx = blockIdx.x;   // 0..7
    int tid = threadIdx.x;
    int w = tid >> 6, lane = tid & 63, quad = lane >> 4, c4 = lane & 15;
    int wm = (w >> 1) * 64, wn = (w & 1) * 64;
    int mbase = my * 128 + wm;
    int nbase = nx * 128 + wn;
    const unsigned short* ob = ot + (size_t)b * 1024 * 256;

    f32x4 acc[4][4] = {};
    for (int k = 0; k < 256; k += 32) {
        bf16x8 af[4], bfr[4];
        for (int i = 0; i < 4; i++) {
            af[i] = *(const bf16x8*)(wpb + (mbase + i * 16 + c4) * 256 + k + quad * 8);
            bfr[i] = *(const bf16x8*)(ob + (size_t)(nbase + i * 16 + c4) * 256 + k + quad * 8);
        }
        for (int mi = 0; mi < 4; mi++)
            for (int ni = 0; ni < 4; ni++)
                acc[mi][ni] = __builtin_amdgcn_mfma_f32_16x16x32_bf16(
                    af[mi], bfr[ni], acc[mi][ni], 0, 0, 0);
    }
    for (int mi = 0; mi < 4; mi++)
        for (int ni = 0; ni < 4; ni++)
            for (int r = 0; r < 4; r++) {
                int o = mbase + mi * 16 + quad * 4 + r;
                int i = nbase + ni * 16 + c4;
                size_t idx = ((size_t)b * 256 + o) * 1024 + i;
                out[idx] = acc[mi][ni][r] + x[idx];
            }
}

// ---------------------------------------------------------------------------
extern "C" void kernel_launch(void* const* d_in, const int* in_sizes, int n_in,
                              void* d_out, int out_size, void* d_ws, size_t ws_size,
                              hipStream_t stream) {
    const float* x   = (const float*)d_in[0];
    const float* gnw = (const float*)d_in[1];
    const float* gnb = (const float*)d_in[2];
    const float* wq  = (const float*)d_in[3];
    const float* wk  = (const float*)d_in[4];
    const float* wv  = (const float*)d_in[5];
    const float* wp  = (const float*)d_in[6];
    float* out = (float*)d_out;

    char* ws = (char*)d_ws;
    float* stats = (float*)ws;                                    //   512 B
    unsigned short* wqb = (unsigned short*)(ws + 512);             // 128 KiB
    unsigned short* wkb = (unsigned short*)(ws + 512 + 131072);
    unsigned short* wvb = (unsigned short*)(ws + 512 + 2 * 131072);
    unsigned short* wpb = (unsigned short*)(ws + 512 + 3 * 131072);
    size_t base = 512 + 4 * 131072;
    const size_t SZ = (size_t)16 * 1024 * 256 * 2;  // 8 MiB each
    unsigned short* xnt = (unsigned short*)(ws + base);
    unsigned short* qt  = (unsigned short*)(ws + base + SZ);
    unsigned short* kt  = (unsigned short*)(ws + base + 2 * SZ);
    unsigned short* vv  = (unsigned short*)(ws + base + 3 * SZ);
    unsigned short* ot  = (unsigned short*)(ws + base + 4 * SZ);

    gn_stats<<<64, 256, 0, stream>>>(x, stats);
    wconv<<<1024, 256, 0, stream>>>(wq, wk, wv, wp, wqb, wkb, wvb, wpb);
    gn_norm<<<dim3(16, 4, 16), 256, 0, stream>>>(x, stats, gnw, gnb, xnt);
    qkv_gemm<<<dim3(8, 6, 16), 256, 0, stream>>>(wqb, wkb, wvb, xnt, qt, kt, vv);
    attn_kernel<<<dim3(8, 2, 16), 256, 0, stream>>>(qt, kt, vv, ot);
    proj_gemm<<<dim3(8, 2, 16), 256, 0, stream>>>(wpb, ot, x, out);
}

// Round 3
// 188.958 us; speedup vs baseline: 1.5709x; 1.5709x over previous
//
#include <hip/hip_runtime.h>
#include <math.h>

// ---------------------------------------------------------------------------
// AttentionBlock: GN(4,256) -> QKV 1x1 conv -> 2-head attn (N=1024, hd=128)
// -> proj -> +residual.  B=16, C=256, H=W=32 (N=1024), fp32 in/out.
// R3: fixes R2's P re-frag shfl bug (register-select must be destination-side;
// pack even/odd n-block bf16 pair into one uint32, select half after shfl).
// ---------------------------------------------------------------------------

typedef __attribute__((ext_vector_type(8))) short bf16x8;   // 8 bf16 = 4 VGPRs
typedef __attribute__((ext_vector_type(4))) float f32x4;

__device__ __forceinline__ unsigned short f2bf(float f) {
    union { float f; unsigned u; } v; v.f = f;
    unsigned r = (v.u + 0x7FFFu + ((v.u >> 16) & 1u)) >> 16;
    return (unsigned short)r;
}

__device__ __forceinline__ void gload_lds16(const void* g, void* l) {
    __builtin_amdgcn_global_load_lds(
        (const __attribute__((address_space(1))) unsigned int*)g,
        (__attribute__((address_space(3))) unsigned int*)l, 16, 0, 0);
}

// ---------------------------------------------------------------- GN stats
// 512 blocks (8 per (b,g)), float4 loads, fp32 atomics into acc (zeroed by
// wconv which is launched first).
__global__ __launch_bounds__(256) void gn_stats(const float* __restrict__ x,
                                                float* __restrict__ acc) {
    int bg = blockIdx.x >> 3, ch = blockIdx.x & 7;
    const float4* xp = (const float4*)(x + (size_t)bg * 65536 + ch * 8192);
    float s = 0.f, s2 = 0.f;
#pragma unroll
    for (int i = 0; i < 8; i++) {
        float4 v = xp[threadIdx.x + i * 256];
        s  += v.x + v.y + v.z + v.w;
        s2 += v.x * v.x + v.y * v.y + v.z * v.z + v.w * v.w;
    }
    for (int m = 1; m < 64; m <<= 1) { s += __shfl_xor(s, m); s2 += __shfl_xor(s2, m); }
    __shared__ float ls[8];
    int w = threadIdx.x >> 6, lane = threadIdx.x & 63;
    if (lane == 0) { ls[w] = s; ls[4 + w] = s2; }
    __syncthreads();
    if (threadIdx.x == 0) {
        atomicAdd(&acc[bg * 2],     ls[0] + ls[1] + ls[2] + ls[3]);
        atomicAdd(&acc[bg * 2 + 1], ls[4] + ls[5] + ls[6] + ls[7]);
    }
}

// --------------------------------------------- normalize + transpose -> bf16
// out Xnt layout: (b, n, c) with c contiguous
__global__ __launch_bounds__(256) void gn_norm(const float* __restrict__ x,
                                               const float* __restrict__ acc,
                                               const float* __restrict__ gnw,
                                               const float* __restrict__ gnb,
                                               unsigned short* __restrict__ xnt) {
    int b = blockIdx.z, ct = blockIdx.y, nt = blockIdx.x;  // (16,4,16)
    float a0 = acc[(b * 4 + ct) * 2], a1 = acc[(b * 4 + ct) * 2 + 1];
    float mean = a0 * (1.f / 65536.f);
    float var = a1 * (1.f / 65536.f) - mean * mean;
    float rstd = rsqrtf(var + 1e-5f);
    __shared__ unsigned short tile[64][66];
    int tid = threadIdx.x;
    int nloc = tid & 63, c0 = tid >> 6;
    for (int i = 0; i < 16; i++) {
        int cl = c0 + i * 4;
        int c = ct * 64 + cl;
        float v = x[((size_t)b * 256 + c) * 1024 + nt * 64 + nloc];
        tile[cl][nloc] = f2bf((v - mean) * rstd * gnw[c] + gnb[c]);
    }
    __syncthreads();
    int cloc = tid & 63, n0 = tid >> 6;
    for (int i = 0; i < 16; i++) {
        int nl = n0 + i * 4;
        int n = nt * 64 + nl;
        xnt[((size_t)b * 1024 + n) * 256 + ct * 64 + cloc] = tile[cloc][nl];
    }
}

// ------------------------------------------------------- weights fp32->bf16
// Also zeroes the 128-float GN accumulator (runs before gn_stats).
__global__ __launch_bounds__(256) void wconv(const float* __restrict__ wq,
                                             const float* __restrict__ wk,
                                             const float* __restrict__ wv,
                                             const float* __restrict__ wp,
                                             unsigned short* __restrict__ oq,
                                             unsigned short* __restrict__ ok,
                                             unsigned short* __restrict__ ov,
                                             unsigned short* __restrict__ op,
                                             float* __restrict__ acc) {
    int idx = blockIdx.x * 256 + threadIdx.x;
    if (blockIdx.x == 0 && threadIdx.x < 128) acc[threadIdx.x] = 0.f;
    int which = idx >> 16, i = idx & 65535;
    const float* src = (which == 0) ? wq : (which == 1) ? wk : (which == 2) ? wv : wp;
    unsigned short* dst = (which == 0) ? oq : (which == 1) ? ok : (which == 2) ? ov : op;
    // fold softmax scale 512^-0.5 AND log2(e) into wq  (softmax done in exp2)
    float scl = (which == 0) ? (0.044194173824159216f * 1.4426950408889634f) : 1.0f;
    dst[i] = f2bf(src[i] * scl);
}

// --------------------------------------------------------------- QKV GEMM
// grid (16,6,16): block = m128 x n64; wave tile 64x32.
__global__ __launch_bounds__(256) void qkv_gemm(const unsigned short* __restrict__ wqb,
                                                const unsigned short* __restrict__ wkb,
                                                const unsigned short* __restrict__ wvb,
                                                const unsigned short* __restrict__ xnt,
                                                unsigned short* __restrict__ qt,
                                                unsigned short* __restrict__ kt,
                                                unsigned short* __restrict__ vv) {
    int b = blockIdx.z;
    int my = blockIdx.y;          // 0..5 : {q,q,k,k,v,v} x 128 rows
    int nx = blockIdx.x;          // 0..15
    int tid = threadIdx.x;
    int w = tid >> 6, lane = tid & 63, quad = lane >> 4, c4 = lane & 15;
    int wm = (w >> 1) * 64, wn = (w & 1) * 32;
    const unsigned short* wptr = (my < 2) ? wqb : (my < 4) ? wkb : wvb;
    int mbase = (my & 1) * 128 + wm;
    int nbase = nx * 64 + wn;
    const unsigned short* xb = xnt + (size_t)b * 1024 * 256;

    f32x4 acc[4][2] = {};
    for (int k = 0; k < 256; k += 32) {
        bf16x8 af[4], bfr[2];
#pragma unroll
        for (int i = 0; i < 4; i++)
            af[i] = *(const bf16x8*)(wptr + (mbase + i * 16 + c4) * 256 + k + quad * 8);
#pragma unroll
        for (int i = 0; i < 2; i++)
            bfr[i] = *(const bf16x8*)(xb + (size_t)(nbase + i * 16 + c4) * 256 + k + quad * 8);
#pragma unroll
        for (int mi = 0; mi < 4; mi++)
#pragma unroll
            for (int ni = 0; ni < 2; ni++)
                acc[mi][ni] = __builtin_amdgcn_mfma_f32_16x16x32_bf16(
                    af[mi], bfr[ni], acc[mi][ni], 0, 0, 0);
    }

    int sel = my >> 1;  // 0=q 1=k 2=v
#pragma unroll
    for (int mi = 0; mi < 4; mi++)
#pragma unroll
        for (int ni = 0; ni < 2; ni++) {
            int o = mbase + mi * 16 + quad * 4;
            int i = nbase + ni * 16 + c4;
            int h = o >> 7, ch = o & 127;
            if (sel < 2) {
                ushort4 pk;
                pk.x = f2bf(acc[mi][ni][0]);
                pk.y = f2bf(acc[mi][ni][1]);
                pk.z = f2bf(acc[mi][ni][2]);
                pk.w = f2bf(acc[mi][ni][3]);
                unsigned short* dst = (sel == 0 ? qt : kt) +
                    (((size_t)(b * 2 + h) * 1024 + i) * 128 + ch);
                *(ushort4*)dst = pk;
            } else {
                for (int r = 0; r < 4; r++)
                    vv[((size_t)(b * 2 + h) * 128 + ch + r) * 1024 + i] =
                        f2bf(acc[mi][ni][r]);
            }
        }
}

// ------------------------------------------------------- flash attention v3
// Transposed-S design. grid (16,2,16)=512 blocks, 4 waves, wave owns 16 rows.
// Per jt: stage K-tile+V-tile (64KB) to LDS in fragment-block layout via
// global_load_lds; S^T = K*Q^T via MFMA; online softmax; P re-frag via
// packed-pair shfl (dest-side half select); O += P*V^T via MFMA.
__global__ __launch_bounds__(256) void attn_kernel(const unsigned short* __restrict__ qt,
                                                   const unsigned short* __restrict__ kt,
                                                   const unsigned short* __restrict__ vv,
                                                   unsigned short* __restrict__ ot) {
    int b = blockIdx.z, h = blockIdx.y, qb4 = blockIdx.x;
    int bh = b * 2 + h;
    int tid = threadIdx.x, w = tid >> 6, lane = tid & 63;
    int quad = lane >> 4, c4 = lane & 15;
    __shared__ __align__(16) unsigned short klds[16384];   // 32 KB
    __shared__ __align__(16) unsigned short vlds[16384];   // 32 KB

    const unsigned short* qp = qt + (size_t)bh * 1024 * 128;
    const unsigned short* kp = kt + (size_t)bh * 1024 * 128;
    const unsigned short* vp = vv + (size_t)bh * 128 * 1024;
    int i0 = qb4 * 64 + w * 16;

    // Q as B-fragments: B[n=i(lane&15)][k], K=128 -> 4 frags (kept in regs)
    bf16x8 bq[4];
#pragma unroll
    for (int kk = 0; kk < 4; kk++)
        bq[kk] = *(const bf16x8*)(qp + (size_t)(i0 + c4) * 128 + kk * 32 + quad * 8);

    float mi = -INFINITY, li = 0.f;      // per lane: row i = i0 + c4 (dup x4 quads)
    f32x4 oacc[8] = {};                  // O[i=quad*4+r][c = n*16+c4]

    for (int jt = 0; jt < 8; jt++) {
        int j0 = jt * 128;
        __syncthreads();   // previous tile fully consumed
        // ---- stage K,V tiles: 64 chunks of 1KB; chunk = fragment block,
        // lane-ordered so consumption ds_read is base + lane*16 (linear).
#pragma unroll
        for (int t = 0; t < 16; t++) {
            int chunk = w * 16 + t;
            if (chunk < 32) {
                int n = chunk >> 2, kk = chunk & 3;
                const unsigned short* g = kp + (size_t)(j0 + n * 16 + c4) * 128 + kk * 32 + quad * 8;
                gload_lds16(g, &klds[chunk * 512]);
            } else {
                int cc = chunk - 32;
                int n = cc >> 2, w4 = cc & 3;
                const unsigned short* g = vp + (size_t)(n * 16 + c4) * 1024 + j0 + w4 * 32 + quad * 8;
                gload_lds16(g, &vlds[cc * 512]);
            }
        }
        __syncthreads();   // staging visible

        // ---- S^T tile: D[j=quad*4+r (+n*16)][i=c4] ; A=K, B=Q
        f32x4 st[8] = {};
#pragma unroll
        for (int n = 0; n < 8; n++)
#pragma unroll
            for (int kk = 0; kk < 4; kk++) {
                bf16x8 ak = *(const bf16x8*)&klds[(n * 4 + kk) * 512 + lane * 8];
                st[n] = __builtin_amdgcn_mfma_f32_16x16x32_bf16(ak, bq[kk], st[n], 0, 0, 0);
            }

        // ---- online softmax over j (values already in log2 units)
        float mx = st[0][0];
#pragma unroll
        for (int n = 0; n < 8; n++)
#pragma unroll
            for (int r = 0; r < 4; r++) mx = fmaxf(mx, st[n][r]);
        mx = fmaxf(mx, __shfl_xor(mx, 16));
        mx = fmaxf(mx, __shfl_xor(mx, 32));
        float mnew = fmaxf(mi, mx);
        float alpha = exp2f(mi - mnew);
        float rs = 0.f;
#pragma unroll
        for (int n = 0; n < 8; n++)
#pragma unroll
            for (int r = 0; r < 4; r++) {
                float p = exp2f(st[n][r] - mnew);
                st[n][r] = p;
                rs += p;
            }
        rs += __shfl_xor(rs, 16);
        rs += __shfl_xor(rs, 32);
        li = li * alpha + rs;
        mi = mnew;
        // rescale O rows (row index quad*4+r lives in lane c4=quad*4+r)
        float ar[4];
#pragma unroll
        for (int r = 0; r < 4; r++) ar[r] = __shfl(alpha, quad * 4 + r);
#pragma unroll
        for (int n = 0; n < 8; n++)
#pragma unroll
            for (int r = 0; r < 4; r++) oacc[n][r] *= ar[r];

        // ---- pack P pairs: pk[np][r] = {bf(st[2np][r]) , bf(st[2np+1][r])<<16}
        unsigned pk[4][4];
#pragma unroll
        for (int np = 0; np < 4; np++)
#pragma unroll
            for (int r = 0; r < 4; r++)
                pk[np][r] = (unsigned)f2bf(st[np * 2][r]) |
                            ((unsigned)f2bf(st[np * 2 + 1][r]) << 16);

        // ---- P re-frag (packed shfl, dest-side half select) + PV.
        // dest lane (quad,c4) needs A[m=c4][k=quad*8+t], j = w4*32 + quad*8 + t:
        //   source lane = (quad&1)*32 + c4 (+16 for t>=4), n-parity = quad>>1.
        int sbase = ((lane & 16) ? 32 : 0) + c4;
        bool hi = (lane & 32) != 0;
#pragma unroll
        for (int w4 = 0; w4 < 4; w4++) {
            bf16x8 pa;
#pragma unroll
            for (int t = 0; t < 4; t++) {
                unsigned u  = (unsigned)__shfl((int)pk[w4][t], sbase);
                unsigned u2 = (unsigned)__shfl((int)pk[w4][t], sbase + 16);
                pa[t]     = (short)(hi ? (u >> 16)  : (u & 0xffffu));
                pa[4 + t] = (short)(hi ? (u2 >> 16) : (u2 & 0xffffu));
            }
#pragma unroll
            for (int n = 0; n < 8; n++) {
                bf16x8 bv = *(const bf16x8*)&vlds[(n * 4 + w4) * 512 + lane * 8];
                oacc[n] = __builtin_amdgcn_mfma_f32_16x16x32_bf16(pa, bv, oacc[n], 0, 0, 0);
            }
        }
    }

    // ---- epilogue: ot (b, i, c) bf16
    float inv = 1.0f / li;
    float ir[4];
#pragma unroll
    for (int r = 0; r < 4; r++) ir[r] = __shfl(inv, quad * 4 + r);
#pragma unroll
    for (int n = 0; n < 8; n++)
#pragma unroll
        for (int r = 0; r < 4; r++) {
            int i = i0 + quad * 4 + r;
            int c = h * 128 + n * 16 + c4;
            ot[((size_t)b * 1024 + i) * 256 + c] = f2bf(oacc[n][r] * ir[r]);
        }
}

// ------------------------------------------------------ proj + residual
// grid (16,2,16): block m128 x n64; wave tile 64x32.
__global__ __launch_bounds__(256) void proj_gemm(const unsigned short* __restrict__ wpb,
                                                 const unsigned short* __restrict__ ot,
                                                 const float* __restrict__ x,
                                                 float* __restrict__ out) {
    int b = blockIdx.z;
    int my = blockIdx.y;   // 0..1
    int nx = blockIdx.x;   // 0..15
    int tid = threadIdx.x;
    int w = tid >> 6, lane = tid & 63, quad = lane >> 4, c4 = lane & 15;
    int wm = (w >> 1) * 64, wn = (w & 1) * 32;
    int mbase = my * 128 + wm;
    int nbase = nx * 64 + wn;
    const unsigned short* ob = ot + (size_t)b * 1024 * 256;

    f32x4 acc[4][2] = {};
    for (int k = 0; k < 256; k += 32) {
        bf16x8 af[4], bfr[2];
#pragma unroll
        for (int i = 0; i < 4; i++)
            af[i] = *(const bf16x8*)(wpb + (mbase + i * 16 + c4) * 256 + k + quad * 8);
#pragma unroll
        for (int i = 0; i < 2; i++)
            bfr[i] = *(const bf16x8*)(ob + (size_t)(nbase + i * 16 + c4) * 256 + k + quad * 8);
#pragma unroll
        for (int mi = 0; mi < 4; mi++)
#pragma unroll
            for (int ni = 0; ni < 2; ni++)
                acc[mi][ni] = __builtin_amdgcn_mfma_f32_16x16x32_bf16(
                    af[mi], bfr[ni], acc[mi][ni], 0, 0, 0);
    }
#pragma unroll
    for (int mi = 0; mi < 4; mi++)
#pragma unroll
        for (int ni = 0; ni < 2; ni++)
#pragma unroll
            for (int r = 0; r < 4; r++) {
                int o = mbase + mi * 16 + quad * 4 + r;
                int i = nbase + ni * 16 + c4;
                size_t idx = ((size_t)b * 256 + o) * 1024 + i;
                out[idx] = acc[mi][ni][r] + x[idx];
            }
}

// ---------------------------------------------------------------------------
extern "C" void kernel_launch(void* const* d_in, const int* in_sizes, int n_in,
                              void* d_out, int out_size, void* d_ws, size_t ws_size,
                              hipStream_t stream) {
    const float* x   = (const float*)d_in[0];
    const float* gnw = (const float*)d_in[1];
    const float* gnb = (const float*)d_in[2];
    const float* wq  = (const float*)d_in[3];
    const float* wk  = (const float*)d_in[4];
    const float* wv  = (const float*)d_in[5];
    const float* wp  = (const float*)d_in[6];
    float* out = (float*)d_out;

    char* ws = (char*)d_ws;
    float* acc = (float*)ws;                                       //   512 B
    unsigned short* wqb = (unsigned short*)(ws + 512);             // 128 KiB each
    unsigned short* wkb = (unsigned short*)(ws + 512 + 131072);
    unsigned short* wvb = (unsigned short*)(ws + 512 + 2 * 131072);
    unsigned short* wpb = (unsigned short*)(ws + 512 + 3 * 131072);
    size_t base = 512 + 4 * 131072;
    const size_t SZ = (size_t)16 * 1024 * 256 * 2;  // 8 MiB each
    unsigned short* xnt = (unsigned short*)(ws + base);
    unsigned short* qt  = (unsigned short*)(ws + base + SZ);
    unsigned short* kt  = (unsigned short*)(ws + base + 2 * SZ);
    unsigned short* vv  = (unsigned short*)(ws + base + 3 * SZ);
    unsigned short* ot  = (unsigned short*)(ws + base + 4 * SZ);

    wconv<<<1024, 256, 0, stream>>>(wq, wk, wv, wp, wqb, wkb, wvb, wpb, acc);
    gn_stats<<<512, 256, 0, stream>>>(x, acc);
    gn_norm<<<dim3(16, 4, 16), 256, 0, stream>>>(x, acc, gnw, gnb, xnt);
    qkv_gemm<<<dim3(16, 6, 16), 256, 0, stream>>>(wqb, wkb, wvb, xnt, qt, kt, vv);
    attn_kernel<<<dim3(16, 2, 16), 256, 0, stream>>>(qt, kt, vv, ot);
    proj_gemm<<<dim3(16, 2, 16), 256, 0, stream>>>(wpb, ot, x, out);
}